// Round 10
// baseline (230.138 us; speedup 1.0000x reference)
//
#include <hip/hip_runtime.h>
#include <cstdint>
#include <cstddef>

#define SEQ   2048
#define EDIM  256
#define FFND  512
#define NBATCH 16
#define XLD   264   // xt row pitch (u16)

typedef unsigned short u16;
typedef __attribute__((ext_vector_type(8))) __bf16 bf16x8;
typedef __attribute__((ext_vector_type(4))) float f32x4;

__device__ __forceinline__ float bf2f(u16 u) {
  union { unsigned int w; float f; } v; v.w = ((unsigned int)u) << 16; return v.f;
}
__device__ __forceinline__ u16 f2bf(float f) {
  union { float f; unsigned int w; } v; v.f = f;
  unsigned int r = v.w + 0x7fffu + ((v.w >> 16) & 1u);
  return (u16)(r >> 16);
}
__device__ __forceinline__ float fast_cos(float x) {
  float r = x * 0.15915494309189535f;
  r = r - floorf(r);
  return __builtin_amdgcn_cosf(r);
}
__device__ __forceinline__ void unpack8(bf16x8 v, float* o) {
  const u16* p = (const u16*)&v;
  #pragma unroll
  for (int j = 0; j < 8; ++j) o[j] = bf2f(p[j]);
}
// self-sniff: read 128 dwords (512 B) of embed; f32 data -> low halves have
// random "exponent" fields (~64 hits); bf16 data -> ~0 hits. No cross-thread dep.
__device__ __forceinline__ int sniff128(const void* embed) {
  const unsigned* p = (const unsigned*)embed;
  int c = 0;
  #pragma unroll
  for (int j = 0; j < 128; ++j) {
    unsigned v = p[j];
    c += (((v >> 7) & 0xffu) > 128u) ? 1 : 0;
    c += (((v >> 23) & 0xffu) > 128u) ? 1 : 0;
  }
  return c > 32;
}
__device__ __forceinline__ float cvt(const void* p, int j, int isf32) {
  return isf32 ? ((const float*)p)[j] : bf2f(((const u16*)p)[j]);
}

struct CanonArgs { const void* p[14]; };

// ---- prep_all: canonical bf16 params + cwT/l2T staging layout + w1f/b1f f32 ----
__global__ void prep_kernel(const void* __restrict__ emb, CanonArgs a,
                            u16* __restrict__ canon, u16* __restrict__ cwT,
                            u16* __restrict__ l2T, float* __restrict__ w1f,
                            float* __restrict__ b1f) {
  const int isf32 = sniff128(emb);
  int id = blockIdx.x * 256 + threadIdx.x;
  if (id < 406162) {
    const int off[15] = {0, 128, 131200, 131712, 131728, 139920, 140944, 403088,
                         403600, 404112, 404624, 405136, 405648, 406160, 406162};
    int s = 0;
    #pragma unroll
    for (int k = 0; k < 13; ++k) s += (id >= off[k + 1]) ? 1 : 0;
    canon[id] = f2bf(cvt(a.p[s], id - off[s], isf32));
  } else if (id < 537234) {
    int j = id - 406162;
    int l = j >> 16, rem = j & 65535;
    int kc = rem >> 11, n = (rem >> 3) & 255, kj = rem & 7;
    cwT[j] = f2bf(cvt(a.p[1], l * 65536 + (kc * 8 + kj) * 256 + n, isf32));
  } else if (id < 799378) {
    int j = id - 537234;
    int l = j >> 17, rem = j & 131071;
    int kc = rem >> 11, n = (rem >> 3) & 255, kj = rem & 7;
    l2T[j] = f2bf(cvt(a.p[6], l * 131072 + (kc * 8 + kj) * 256 + n, isf32));
  } else if (id < 807570) {
    int j = id - 799378;                 // [2][8][512] plain
    w1f[j] = cvt(a.p[4], j, isf32);
  } else if (id < 808594) {
    int j = id - 807570;                 // [2][512]
    b1f[j] = cvt(a.p[5], j, isf32);
  }
}

// ====== MEGA: embed+PE -> [attn GEMM+LN1 -> q -> ffn GEMM+LN2] x2 -> pool ======
__launch_bounds__(256, 2)
__global__ void mega_kernel(const int* __restrict__ tokens, const void* __restrict__ embed,
                            const u16* __restrict__ canon, const u16* __restrict__ cwT,
                            const u16* __restrict__ l2T, const float* __restrict__ w1f,
                            const float* __restrict__ b1f, float* __restrict__ pooled) {
  __shared__ u16 xt[64 * XLD];          // 33792 B persistent x tile
  __shared__ union {
    struct { u16 Bt[256 * 64]; u16 At[64 * 64]; float qsf[64 * 8]; } k;  // 43008 B
    struct { float2 part[64][65]; float2 ms[64]; } ln;                    // 34304 B
  } sh;
  __shared__ u16 thL[64];

  const int tid = threadIdx.x;
  const int wave = tid >> 6, lane = tid & 63;
  const int fr = lane & 15, fq = lane >> 4;
  const int m0 = blockIdx.x * 64;
  const int isf32 = sniff128(embed);

  int cols[4];
  #pragma unroll
  for (int ni = 0; ni < 4; ++ni) cols[ni] = wave * 64 + ni * 16 + fr;

  // ---------- embed + inline PE -> xt ----------
  {
    const float c0 = 9.210340371976184f / 128.f;   // ln(10000)/128
    const float inv2pi = 0.15915494309189535f;
    #pragma unroll
    for (int it = 0; it < 8; ++it) {
      int c = it * 256 + tid;
      int r = c >> 5, e8 = c & 31;
      int tok = tokens[m0 + r];
      float ev[8];
      if (isf32) {
        const float* ep = (const float*)embed + (size_t)tok * EDIM + e8 * 8;
        float4 a = *(const float4*)ep, b = *(const float4*)(ep + 4);
        ev[0]=a.x; ev[1]=a.y; ev[2]=a.z; ev[3]=a.w; ev[4]=b.x; ev[5]=b.y; ev[6]=b.z; ev[7]=b.w;
      } else {
        const u16* ep = (const u16*)embed + (size_t)tok * EDIM + e8 * 8;
        uint4 v = *(const uint4*)ep;
        unpack8(*(const bf16x8*)&v, ev);
      }
      int s = (m0 + r) & (SEQ - 1);
      u16 o[8];
      #pragma unroll
      for (int j = 0; j < 8; ++j) {
        int e = e8 * 8 + j, i = e >> 1;
        float rev = (float)s * (__expf(-(float)i * c0) * inv2pi);
        rev = rev - floorf(rev);
        float pe = (e & 1) ? __builtin_amdgcn_cosf(rev) : __builtin_amdgcn_sinf(rev);
        o[j] = f2bf(ev[j] + pe);
      }
      *(uint4*)(xt + r * XLD + e8 * 8) = *(const uint4*)o;
    }
  }
  __syncthreads();

  f32x4 acc[4][4];

  auto mfma_step = [&]() {
    const bf16x8* Av = (const bf16x8*)sh.k.At;
    const bf16x8* Bv = (const bf16x8*)sh.k.Bt;
    #pragma unroll
    for (int ks = 0; ks < 2; ++ks) {
      const int kc = ks * 4 + fq;
      bf16x8 af[4], bfv[4];
      #pragma unroll
      for (int mi = 0; mi < 4; ++mi) af[mi] = Av[kc * 64 + ((mi * 16 + fr) ^ kc)];
      #pragma unroll
      for (int ni = 0; ni < 4; ++ni) bfv[ni] = Bv[kc * 256 + cols[ni]];
      #pragma unroll
      for (int mi = 0; mi < 4; ++mi)
        #pragma unroll
        for (int ni = 0; ni < 4; ++ni)
          acc[mi][ni] = __builtin_amdgcn_mfma_f32_16x16x32_bf16(af[mi], bfv[ni], acc[mi][ni], 0, 0, 0);
    }
  };

  // bias + residual + LN (partial-dump reduction)
  auto epilogue = [&](const u16* bias, const u16* gamma, const u16* beta) {
    float bcol[4];
    #pragma unroll
    for (int ni = 0; ni < 4; ++ni) bcol[ni] = bf2f(bias[cols[ni]]);
    #pragma unroll
    for (int mi = 0; mi < 4; ++mi)
      #pragma unroll
      for (int rg = 0; rg < 4; ++rg) {
        int lrow = mi * 16 + fq * 4 + rg;
        float a = 0.f, b = 0.f;
        #pragma unroll
        for (int ni = 0; ni < 4; ++ni) {
          float t2 = acc[mi][ni][rg] + bf2f(xt[lrow * XLD + cols[ni]]) + bcol[ni];
          acc[mi][ni][rg] = t2;
          a += t2; b += t2 * t2;
        }
        sh.ln.part[lrow][wave * 16 + fr] = float2{a, b};
      }
    __syncthreads();
    if (tid < 64) {
      float s = 0.f, s2 = 0.f;
      #pragma unroll
      for (int f = 0; f < 64; f += 2) {
        float4 p = *(const float4*)&sh.ln.part[tid][f];
        s += p.x + p.z; s2 += p.y + p.w;
      }
      float mean = s * (1.f / 256.f);
      float var = fmaxf(s2 * (1.f / 256.f) - mean * mean, 0.f);
      sh.ln.ms[tid] = float2{mean, rsqrtf(var + 1e-5f)};
    }
    __syncthreads();
    float gcol[4], btc[4];
    #pragma unroll
    for (int ni = 0; ni < 4; ++ni) { gcol[ni] = bf2f(gamma[cols[ni]]); btc[ni] = bf2f(beta[cols[ni]]); }
    #pragma unroll
    for (int mi = 0; mi < 4; ++mi)
      #pragma unroll
      for (int rg = 0; rg < 4; ++rg) {
        int lrow = mi * 16 + fq * 4 + rg;
        float2 ms = sh.ln.ms[lrow];
        #pragma unroll
        for (int ni = 0; ni < 4; ++ni) {
          float o = (acc[mi][ni][rg] - ms.x) * ms.y * gcol[ni] + btc[ni];
          xt[lrow * XLD + cols[ni]] = f2bf(o);
        }
      }
    __syncthreads();
  };

  for (int l = 0; l < 2; ++l) {
    // ---------- attn: acc = cos(xt + theta) @ cwT ----------
    if (tid < 8) ((uint4*)thL)[tid] = ((const uint4*)(canon + l * 64))[tid];
    __syncthreads();
    #pragma unroll
    for (int i = 0; i < 4; ++i)
      #pragma unroll
      for (int j = 0; j < 4; ++j) acc[i][j] = {0.f, 0.f, 0.f, 0.f};
    {
      const u16* Bbase = cwT + l * 65536;
      for (int k0 = 0; k0 < 256; k0 += 64) {
        const u16* bsrc = Bbase + (k0 >> 3) * 2048;
        #pragma unroll
        for (int it = 0; it < 8; ++it) {
          int c = tid + it * 256;
          __builtin_amdgcn_global_load_lds(
              (const __attribute__((address_space(1))) void*)(bsrc + (size_t)c * 8),
              (__attribute__((address_space(3))) void*)(sh.k.Bt + c * 8), 16, 0, 0);
        }
        #pragma unroll
        for (int it = 0; it < 2; ++it) {
          int c = it * 256 + tid;
          int f8 = c >> 6, r = c & 63;
          uint4 g = *(const uint4*)(xt + r * XLD + k0 + f8 * 8);
          u16* gp = (u16*)&g;
          #pragma unroll
          for (int j = 0; j < 8; ++j)
            gp[j] = f2bf(fast_cos(bf2f(gp[j]) + bf2f(thL[f8 * 8 + j])));
          ((uint4*)sh.k.At)[f8 * 64 + (r ^ f8)] = g;
        }
        __syncthreads();
        mfma_step();
        __syncthreads();
      }
    }
    epilogue(canon + 131200 + l * 256, canon + 403600 + l * 256, canon + 404112 + l * 256);

    // ---------- q = cos(xt[:, :8]) * cos(ffn_theta) -> qsf (f32) ----------
    #pragma unroll
    for (int rep = 0; rep < 2; ++rep) {
      int idx = tid + rep * 256;
      int r = idx >> 3, n = idx & 7;
      float cth = fast_cos(bf2f(canon[131712 + l * 8 + n]));
      sh.k.qsf[r * 8 + n] = fast_cos(bf2f(xt[r * XLD + n])) * cth;
    }
    __syncthreads();

    // ---------- ffn: h = relu(q @ W1 + b1) in VALU (f32 weights); acc += h @ l2T ----------
    #pragma unroll
    for (int i = 0; i < 4; ++i)
      #pragma unroll
      for (int j = 0; j < 4; ++j) acc[i][j] = {0.f, 0.f, 0.f, 0.f};
    {
      const u16* B2 = l2T + l * 131072;
      const float* w1l = w1f + l * 4096;
      const float* b1l = b1f + l * 512;
      for (int k0 = 0; k0 < 512; k0 += 64) {
        const u16* bsrc = B2 + (k0 >> 3) * 2048;
        #pragma unroll
        for (int it = 0; it < 8; ++it) {
          int c = tid + it * 256;
          __builtin_amdgcn_global_load_lds(
              (const __attribute__((address_space(1))) void*)(bsrc + (size_t)c * 8),
              (__attribute__((address_space(3))) void*)(sh.k.Bt + c * 8), 16, 0, 0);
        }
        #pragma unroll
        for (int it = 0; it < 2; ++it) {
          int c = it * 256 + tid;
          int kc = c >> 6, r = c & 63;       // kc wave-uniform
          int cc = (k0 >> 3) + kc;           // global 8-col chunk of h
          float4 qa = *(const float4*)(sh.k.qsf + r * 8);
          float4 qb = *(const float4*)(sh.k.qsf + r * 8 + 4);
          float qv[8] = {qa.x, qa.y, qa.z, qa.w, qb.x, qb.y, qb.z, qb.w};
          float hv[8];
          {
            float4 b0 = *(const float4*)(b1l + cc * 8);
            float4 b1v = *(const float4*)(b1l + cc * 8 + 4);
            hv[0]=b0.x; hv[1]=b0.y; hv[2]=b0.z; hv[3]=b0.w;
            hv[4]=b1v.x; hv[5]=b1v.y; hv[6]=b1v.z; hv[7]=b1v.w;
          }
          #pragma unroll
          for (int n = 0; n < 8; ++n) {
            float4 w0 = *(const float4*)(w1l + n * 512 + cc * 8);      // wave-uniform, L1-hot
            float4 w1v = *(const float4*)(w1l + n * 512 + cc * 8 + 4);
            hv[0] += qv[n] * w0.x;  hv[1] += qv[n] * w0.y;
            hv[2] += qv[n] * w0.z;  hv[3] += qv[n] * w0.w;
            hv[4] += qv[n] * w1v.x; hv[5] += qv[n] * w1v.y;
            hv[6] += qv[n] * w1v.z; hv[7] += qv[n] * w1v.w;
          }
          uint4 g; u16* gp = (u16*)&g;
          #pragma unroll
          for (int j = 0; j < 8; ++j) gp[j] = f2bf(fmaxf(hv[j], 0.f));
          ((uint4*)sh.k.At)[kc * 64 + (r ^ kc)] = g;
        }
        __syncthreads();
        mfma_step();
        __syncthreads();
      }
    }
    epilogue(canon + 403088 + l * 256, canon + 404624 + l * 256, canon + 405136 + l * 256);
  }

  // ---------- pool ----------
  {
    float s = 0.f;
    #pragma unroll 8
    for (int r = 0; r < 64; ++r) s += bf2f(xt[r * XLD + tid]);
    atomicAdd(&pooled[(m0 >> 11) * EDIM + tid], s);
  }
}

__global__ void logits_kernel(const float* __restrict__ pooled, const u16* __restrict__ clsw,
                              const u16* __restrict__ clsb, const void* __restrict__ embed,
                              void* __restrict__ out) {
  const int isf32 = sniff128(embed);
  int t = threadIdx.x;
  int b = t >> 4, sub = t & 15;
  float a0 = 0.f, a1 = 0.f;
  #pragma unroll
  for (int j = 0; j < 16; ++j) {
    int e = sub * 16 + j;
    float p = pooled[b * 256 + e];
    a0 += p * bf2f(clsw[e * 2 + 0]);
    a1 += p * bf2f(clsw[e * 2 + 1]);
  }
  #pragma unroll
  for (int d = 1; d < 16; d <<= 1) {
    a0 += __shfl_xor(a0, d);
    a1 += __shfl_xor(a1, d);
  }
  if (sub == 0) {
    float o0 = a0 * (1.f / 2048.f) + bf2f(clsb[0]);
    float o1 = a1 * (1.f / 2048.f) + bf2f(clsb[1]);
    if (isf32) {
      ((float*)out)[b * 2 + 0] = o0; ((float*)out)[b * 2 + 1] = o1;
    } else {
      ((u16*)out)[b * 2 + 0] = f2bf(o0); ((u16*)out)[b * 2 + 1] = f2bf(o1);
    }
  }
}

extern "C" void kernel_launch(void* const* d_in, const int* in_sizes, int n_in,
                              void* d_out, int out_size, void* d_ws, size_t ws_size,
                              hipStream_t stream) {
  const int* tokens = (const int*)d_in[0];

  char* ws = (char*)d_ws;
  u16*   canon  = (u16*)(ws + 0);              // 812 KB bf16 params
  u16*   cwT    = (u16*)(ws + 1048576);        // 256 KB [2][K/8][256][8]
  u16*   l2T    = (u16*)(ws + 1310720);        // 512 KB
  float* w1f    = (float*)(ws + 1835008);      //  32 KB [2][8][512] f32
  float* b1f    = (float*)(ws + 1867776);      //   4 KB [2][512] f32
  float* pooled = (float*)(ws + 1871872);      //  16 KB

  CanonArgs ca;
  for (int i = 0; i < 14; ++i) ca.p[i] = d_in[i + 2];

  prep_kernel<<<3159, 256, 0, stream>>>(d_in[1], ca, canon, cwT, l2T, w1f, b1f);
  hipMemsetAsync(pooled, 0, NBATCH * EDIM * sizeof(float), stream);

  mega_kernel<<<512, 256, 0, stream>>>(tokens, d_in[1], canon, cwT, l2T, w1f, b1f, pooled);

  logits_kernel<<<1, 256, 0, stream>>>(pooled, canon + 405648, canon + 406160, d_in[1], d_out);
}